// Round 6
// baseline (474.650 us; speedup 1.0000x reference)
//
#include <hip/hip_runtime.h>

#define DIM   1024
#define SEQ   2048
#define NH    16
#define HD    64

typedef __attribute__((ext_vector_type(8))) short frag_ab;
typedef __attribute__((ext_vector_type(4))) float f32x4;

__device__ __forceinline__ ushort f32_bf16_rne(float f) {
  union { float f; unsigned int u; } v; v.f = f;
  unsigned int u = v.u + 0x7FFFu + ((v.u >> 16) & 1u);
  return (ushort)(u >> 16);
}

__device__ __forceinline__ void split_bf16(float f, ushort& h, ushort& l) {
  h = f32_bf16_rne(f);
  union { unsigned int u; float f; } hv; hv.u = ((unsigned int)h) << 16;
  l = f32_bf16_rne(f - hv.f);
}

__device__ __forceinline__ void gl2lds16(const void* g, void* l) {
  __builtin_amdgcn_global_load_lds(
      (const __attribute__((address_space(1))) unsigned int*)g,
      (__attribute__((address_space(3))) unsigned int*)l, 16, 0, 0);
}

__device__ __forceinline__ unsigned int asuint(float f) {
  union { float f; unsigned int u; } v; v.f = f; return v.u;
}

#if __has_builtin(__builtin_amdgcn_exp2f)
#define EXP2F(x) __builtin_amdgcn_exp2f(x)
#else
#define EXP2F(x) exp2f(x)
#endif

// ---------------------------------------------------------------------------
// cast_x: fp32 -> bf16 copy.
// ---------------------------------------------------------------------------
__global__ __launch_bounds__(256) void cast_x(const float* __restrict__ x,
                                              ushort* __restrict__ xb) {
  int i = (blockIdx.x * 256 + threadIdx.x) * 8;
  float4 a = *(const float4*)(x + i);
  float4 b = *(const float4*)(x + i + 4);
  uint4 o;
  o.x = (unsigned int)f32_bf16_rne(a.x) | ((unsigned int)f32_bf16_rne(a.y) << 16);
  o.y = (unsigned int)f32_bf16_rne(a.z) | ((unsigned int)f32_bf16_rne(a.w) << 16);
  o.z = (unsigned int)f32_bf16_rne(b.x) | ((unsigned int)f32_bf16_rne(b.y) << 16);
  o.w = (unsigned int)f32_bf16_rne(b.z) | ((unsigned int)f32_bf16_rne(b.w) << 16);
  *(uint4*)(xb + i) = o;
}

// ---------------------------------------------------------------------------
// tcast: transpose + cast W [K][N] f32 -> Wt [N][K] bf16 (opt. hi/lo split).
// ---------------------------------------------------------------------------
template <bool SPLIT>
__global__ __launch_bounds__(256) void tcast(const float* __restrict__ in,
                                             int K, int N,
                                             ushort* __restrict__ outh,
                                             ushort* __restrict__ outl) {
  __shared__ __align__(16) ushort Th[64][72];
  __shared__ __align__(16) ushort Tl[64][72];
  const int kb = blockIdx.y * 64, nb = blockIdx.x * 64;
  const int t = threadIdx.x;
  const int kr = t >> 4, nc = (t & 15) * 4;
#pragma unroll
  for (int j = 0; j < 4; ++j) {
    int k = kr + j * 16;
    float4 v = *(const float4*)&in[(size_t)(kb + k) * N + nb + nc];
    float vv[4] = {v.x, v.y, v.z, v.w};
#pragma unroll
    for (int i = 0; i < 4; ++i) {
      if (SPLIT) {
        ushort h, l; split_bf16(vv[i], h, l);
        Th[nc + i][k] = h; Tl[nc + i][k] = l;
      } else {
        Th[nc + i][k] = f32_bf16_rne(vv[i]);
      }
    }
  }
  __syncthreads();
  const int n = t >> 2, kc = (t & 3) * 16;
  *(uint4*)&outh[(size_t)(nb + n) * K + kb + kc]     = *(const uint4*)&Th[n][kc];
  *(uint4*)&outh[(size_t)(nb + n) * K + kb + kc + 8] = *(const uint4*)&Th[n][kc + 8];
  if (SPLIT) {
    *(uint4*)&outl[(size_t)(nb + n) * K + kb + kc]     = *(const uint4*)&Tl[n][kc];
    *(uint4*)&outl[(size_t)(nb + n) * K + kb + kc + 8] = *(const uint4*)&Tl[n][kc + 8];
  }
}

// ---------------------------------------------------------------------------
// qkv_mfma (verified r2-r5): C = Xb @ Wqt^T (+bias) -> Q, K, V^T bf16.
// K is pre-scaled by SCALE*log2(e) so the attn score MFMA output is directly
// the exp2 argument.
// ---------------------------------------------------------------------------
__global__ __launch_bounds__(256) void qkv_mfma(
    const ushort* __restrict__ Xb, const ushort* __restrict__ Wqt,
    const float* __restrict__ bias,
    ushort* __restrict__ Qw, ushort* __restrict__ Kw, ushort* __restrict__ Vtw) {
  __shared__ __align__(16) ushort As[128 * 32];
  __shared__ __align__(16) ushort Bs[128 * 32];
  const int t = threadIdx.x, wave = t >> 6, lane = t & 63;
  const int ml = lane & 15, quad = lane >> 4;
  const int m0 = blockIdx.y * 128, n0 = blockIdx.x * 128;
  const int wm = (wave & 1) * 64, wn = (wave >> 1) * 64;
  const int srow = lane >> 2, scol = (lane & 3) * 8;
  const int r0 = wave * 16, r1 = (4 + wave) * 16;

  const ushort* Ag = Xb  + (size_t)(m0 + srow) * DIM + scol;
  const ushort* Bg = Wqt + (size_t)(n0 + srow) * DIM + scol;

  f32x4 acc[4][4];
#pragma unroll
  for (int i = 0; i < 4; ++i)
#pragma unroll
    for (int j = 0; j < 4; ++j) acc[i][j] = (f32x4){0.f, 0.f, 0.f, 0.f};

  for (int k0 = 0; k0 < DIM; k0 += 32) {
    __syncthreads();
    gl2lds16(Ag + (size_t)r0 * DIM + k0, &As[r0 * 32]);
    gl2lds16(Ag + (size_t)r1 * DIM + k0, &As[r1 * 32]);
    gl2lds16(Bg + (size_t)r0 * DIM + k0, &Bs[r0 * 32]);
    gl2lds16(Bg + (size_t)r1 * DIM + k0, &Bs[r1 * 32]);
    __syncthreads();
    frag_ab af[4], bfr[4];
#pragma unroll
    for (int im = 0; im < 4; ++im)
      af[im] = *(const frag_ab*)&As[(wm + im * 16 + ml) * 32 + quad * 8];
#pragma unroll
    for (int in_ = 0; in_ < 4; ++in_)
      bfr[in_] = *(const frag_ab*)&Bs[(wn + in_ * 16 + ml) * 32 + quad * 8];
#pragma unroll
    for (int im = 0; im < 4; ++im)
#pragma unroll
      for (int in_ = 0; in_ < 4; ++in_)
        acc[im][in_] = __builtin_amdgcn_mfma_f32_16x16x32_bf16(
            af[im], bfr[in_], acc[im][in_], 0, 0, 0);
  }

  const int t3 = n0 >> 10;
  const int b  = m0 >> 11;
  const int s0 = (m0 & (SEQ - 1)) + wm + quad * 4;
#pragma unroll
  for (int in_ = 0; in_ < 4; ++in_) {
    int n = n0 + wn + in_ * 16 + ml;
    int h = (n >> 6) & 15, d = n & 63;
    float bv = bias[n];
    size_t bh = (size_t)(b * NH + h);
    if (t3 == 2) {
#pragma unroll
      for (int im = 0; im < 4; ++im) {
        int s = s0 + im * 16;
        ushort4 v;
        v.x = f32_bf16_rne(acc[im][in_][0] + bv);
        v.y = f32_bf16_rne(acc[im][in_][1] + bv);
        v.z = f32_bf16_rne(acc[im][in_][2] + bv);
        v.w = f32_bf16_rne(acc[im][in_][3] + bv);
        *(ushort4*)&Vtw[(bh * HD + d) * SEQ + s] = v;
      }
    } else {
      ushort* dst = (t3 == 0) ? Qw : Kw;
      const float m = (t3 == 0) ? 1.0f : 0.18033688011112043f; // SCALE*log2e
#pragma unroll
      for (int im = 0; im < 4; ++im)
#pragma unroll
        for (int r = 0; r < 4; ++r)
          dst[(bh * SEQ + s0 + im * 16 + r) * HD + d] =
              f32_bf16_rne((acc[im][in_][r] + bv) * m);
    }
  }
}

// ---------------------------------------------------------------------------
// attn: barrier-free flash attention, all operands direct global->VGPR.
//  - wave w privately owns keys [w*512, (w+1)*512) of its (bh, 64-query tile)
//  - no LDS, no DMA, no __syncthreads in the K-loop: every MFMA operand is a
//    16B/8B contiguous row segment (K[key][dims], Q[q][dims], V^T[d][keys]),
//    loaded straight to VGPRs; compiler tracks deps via normal vmcnt
//  - per 32-key chunk: 4 SC mfma32 + 32 exp2 + RNE pack + 4 PV mfma32
//    (PV key-permutation identical to verified round 5)
//  - epilogue (cross-wave LDS reduce + normalize + hi/lo split) unchanged;
//    LDS = 17.7 KB, used only after the loop
// ---------------------------------------------------------------------------
__global__ __launch_bounds__(256, 3) void attn_kernel(
    const ushort* Qw, const ushort* __restrict__ Kw,
    const ushort* __restrict__ Vtw, ushort* Ohw, ushort* Olw) {
  __shared__ __align__(16) char smem[17664];
  float* Ored = (float*)smem;                  // [64][65] f32 (16640 B)
  float* lsum_buf = (float*)(smem + 16640);    // [4][64]  f32 (1024 B)

  const int t = threadIdx.x, wave = t >> 6, lane = t & 63;
  const int ml = lane & 15, quad = lane >> 4;
  const int bid = blockIdx.x;
  const int bh  = (bid & 7) | ((bid >> 8) << 3);
  const int qt0 = (bid >> 3) & 31;

  const ushort* Qg = Qw + ((size_t)bh * SEQ + qt0 * 64) * HD;
  const ushort* Kg = Kw + ((size_t)bh * SEQ + wave * 512) * HD;
  const ushort* Vg = Vtw + (size_t)bh * HD * SEQ + wave * 512;

  // Q fragments: held in registers for the whole kernel
  frag_ab qf[4][2];
#pragma unroll
  for (int qt = 0; qt < 4; ++qt)
#pragma unroll
    for (int h = 0; h < 2; ++h)
      qf[qt][h] = *(const frag_ab*)&Qg[(qt * 16 + ml) * HD + h * 32 + quad * 8];

  f32x4 acc[4][4];
#pragma unroll
  for (int i = 0; i < 4; ++i)
#pragma unroll
    for (int j = 0; j < 4; ++j) acc[i][j] = (f32x4){0.f, 0.f, 0.f, 0.f};
  float lsum[4] = {0.f, 0.f, 0.f, 0.f};

#pragma unroll 1
  for (int c = 0; c < 16; ++c) {
    const int k0 = c * 32;
    // K fragments: keys k0..k0+31 as two 16-key tiles, dims split 0..31/32..63
    frag_ab ak00 = *(const frag_ab*)&Kg[(k0 + ml) * HD + quad * 8];
    frag_ab ak01 = *(const frag_ab*)&Kg[(k0 + ml) * HD + 32 + quad * 8];
    frag_ab ak10 = *(const frag_ab*)&Kg[(k0 + 16 + ml) * HD + quad * 8];
    frag_ab ak11 = *(const frag_ab*)&Kg[(k0 + 16 + ml) * HD + 32 + quad * 8];
    // V fragments in the PERMUTED key order matching P below:
    // j=0..3 -> keys k0+4*quad+j ; j=4..7 -> keys k0+16+4*quad+(j-4)
    frag_ab av[4];
#pragma unroll
    for (int dt = 0; dt < 4; ++dt) {
      const ushort* vrow = Vg + (size_t)(dt * 16 + ml) * SEQ + k0 + 4 * quad;
      union { uint2 h[2]; frag_ab f; } u;
      u.h[0] = *(const uint2*)(vrow);
      u.h[1] = *(const uint2*)(vrow + 16);
      av[dt] = u.f;
    }

#pragma unroll
    for (int qt = 0; qt < 4; ++qt) {
      f32x4 s0 = __builtin_amdgcn_mfma_f32_16x16x32_bf16(
          ak00, qf[qt][0], (f32x4){0.f, 0.f, 0.f, 0.f}, 0, 0, 0);
      s0 = __builtin_amdgcn_mfma_f32_16x16x32_bf16(ak01, qf[qt][1], s0, 0, 0, 0);
      f32x4 s1 = __builtin_amdgcn_mfma_f32_16x16x32_bf16(
          ak10, qf[qt][0], (f32x4){0.f, 0.f, 0.f, 0.f}, 0, 0, 0);
      s1 = __builtin_amdgcn_mfma_f32_16x16x32_bf16(ak11, qf[qt][1], s1, 0, 0, 0);
      float e0 = EXP2F(s0[0]), e1 = EXP2F(s0[1]);
      float e2 = EXP2F(s0[2]), e3 = EXP2F(s0[3]);
      float e4 = EXP2F(s1[0]), e5 = EXP2F(s1[1]);
      float e6 = EXP2F(s1[2]), e7 = EXP2F(s1[3]);
      lsum[qt] += ((e0 + e1) + (e2 + e3)) + ((e4 + e5) + (e6 + e7));
      union { unsigned int i[4]; frag_ab f; } pv;
      pv.i[0] = __builtin_amdgcn_perm(asuint(e1) + 0x8000u,
                                      asuint(e0) + 0x8000u, 0x07060302u);
      pv.i[1] = __builtin_amdgcn_perm(asuint(e3) + 0x8000u,
                                      asuint(e2) + 0x8000u, 0x07060302u);
      pv.i[2] = __builtin_amdgcn_perm(asuint(e5) + 0x8000u,
                                      asuint(e4) + 0x8000u, 0x07060302u);
      pv.i[3] = __builtin_amdgcn_perm(asuint(e7) + 0x8000u,
                                      asuint(e6) + 0x8000u, 0x07060302u);
#pragma unroll
      for (int dt = 0; dt < 4; ++dt)
        acc[dt][qt] = __builtin_amdgcn_mfma_f32_16x16x32_bf16(
            av[dt], pv.f, acc[dt][qt], 0, 0, 0);
    }
  }

  // quad-reduce lsum within wave (each lane covered 8 keys/chunk; quads tile 32)
#pragma unroll
  for (int qt = 0; qt < 4; ++qt) {
    float s = lsum[qt];
    s += __shfl_xor(s, 16, 64);
    s += __shfl_xor(s, 32, 64);
    lsum[qt] = s;
  }

  __syncthreads();   // only barrier: all waves done with their K-loop
  if (quad == 0) {
#pragma unroll
    for (int qt = 0; qt < 4; ++qt) lsum_buf[wave * 64 + qt * 16 + ml] = lsum[qt];
  }
  if (wave == 0) {
#pragma unroll
    for (int dt = 0; dt < 4; ++dt)
#pragma unroll
      for (int qt = 0; qt < 4; ++qt)
#pragma unroll
        for (int r = 0; r < 4; ++r)
          Ored[(dt * 16 + quad * 4 + r) * 65 + qt * 16 + ml] = acc[dt][qt][r];
  }
  __syncthreads();
  if (wave != 0) {
#pragma unroll
    for (int dt = 0; dt < 4; ++dt)
#pragma unroll
      for (int qt = 0; qt < 4; ++qt)
#pragma unroll
        for (int r = 0; r < 4; ++r)
          atomicAdd(&Ored[(dt * 16 + quad * 4 + r) * 65 + qt * 16 + ml],
                    acc[dt][qt][r]);
  }
  __syncthreads();

  // normalize + hi/lo bf16 split, coalesced store
  const int q = t >> 2, d0 = (t & 3) * 16;
  const float inv = 1.0f / (lsum_buf[q] + lsum_buf[64 + q] +
                            lsum_buf[128 + q] + lsum_buf[192 + q]);
  size_t rowb = ((size_t)bh * SEQ + qt0 * 64 + q) * HD + d0;
#pragma unroll
  for (int g = 0; g < 2; ++g) {
    unsigned int hu[4], lu[4];
#pragma unroll
    for (int j = 0; j < 4; ++j) {
      float f0 = Ored[(d0 + g * 8 + 2 * j) * 65 + q] * inv;
      float f1 = Ored[(d0 + g * 8 + 2 * j + 1) * 65 + q] * inv;
      ushort h0, l0, h1, l1;
      split_bf16(f0, h0, l0);
      split_bf16(f1, h1, l1);
      hu[j] = (unsigned int)h0 | ((unsigned int)h1 << 16);
      lu[j] = (unsigned int)l0 | ((unsigned int)l1 << 16);
    }
    uint4 hv = {hu[0], hu[1], hu[2], hu[3]};
    uint4 lv = {lu[0], lu[1], lu[2], lu[3]};
    *(uint4*)&Ohw[rowb + g * 8] = hv;
    *(uint4*)&Olw[rowb + g * 8] = lv;
  }
}

// ---------------------------------------------------------------------------
// proj_mfma (verified): out = (Oh+Ol) @ (Wh+Wl)^T + bias.
// ---------------------------------------------------------------------------
__global__ __launch_bounds__(256) void proj_mfma(
    const ushort* __restrict__ Oh, const ushort* __restrict__ Ol,
    const ushort* __restrict__ Wph, const ushort* __restrict__ Wpl,
    const float* __restrict__ bias, float* __restrict__ out) {
  __shared__ __align__(16) ushort As[128 * 32];
  __shared__ __align__(16) ushort Bs[128 * 32];
  const int t = threadIdx.x, wave = t >> 6, lane = t & 63;
  const int ml = lane & 15, quad = lane >> 4;
  const int m0 = blockIdx.y * 128, n0 = blockIdx.x * 128;
  const int wm = (wave & 1) * 64, wn = (wave >> 1) * 64;
  const int srow = lane >> 2, scol = (lane & 3) * 8;
  const int r0 = wave * 16, r1 = (4 + wave) * 16;
  const int b = m0 >> 11, s0r = m0 & (SEQ - 1);

  f32x4 acc[4][4];
#pragma unroll
  for (int i = 0; i < 4; ++i)
#pragma unroll
    for (int j = 0; j < 4; ++j) acc[i][j] = (f32x4){0.f, 0.f, 0.f, 0.f};

  for (int kt = 0; kt < 96; ++kt) {
    int ph = kt >> 5;
    int kv = (kt & 31) * 32;
    const ushort* Asrc = (ph == 1) ? Ol : Oh;
    const ushort* Bsrc = (ph == 2) ? Wpl : Wph;
    int h = kv >> 6, dbase = kv & 63;
    const ushort* Ag = Asrc + (((size_t)(b * NH + h) * SEQ) + s0r + srow) * HD
                            + dbase + scol;
    const ushort* Bg = Bsrc + (size_t)(n0 + srow) * DIM + kv + scol;
    __syncthreads();
    gl2lds16(Ag + (size_t)r0 * HD, &As[r0 * 32]);
    gl2lds16(Ag + (size_t)r1 * HD, &As[r1 * 32]);
    gl2lds16(Bg + (size_t)r0 * DIM, &Bs[r0 * 32]);
    gl2lds16(Bg + (size_t)r1 * DIM, &Bs[r1 * 32]);
    __syncthreads();
    frag_ab af[4], bfr[4];
#pragma unroll
    for (int im = 0; im < 4; ++im)
      af[im] = *(const frag_ab*)&As[(wm + im * 16 + ml) * 32 + quad * 8];
#pragma unroll
    for (int in_ = 0; in_ < 4; ++in_)
      bfr[in_] = *(const frag_ab*)&Bs[(wn + in_ * 16 + ml) * 32 + quad * 8];
#pragma unroll
    for (int im = 0; im < 4; ++im)
#pragma unroll
      for (int in_ = 0; in_ < 4; ++in_)
        acc[im][in_] = __builtin_amdgcn_mfma_f32_16x16x32_bf16(
            af[im], bfr[in_], acc[im][in_], 0, 0, 0);
  }

#pragma unroll
  for (int in_ = 0; in_ < 4; ++in_) {
    int n = n0 + wn + in_ * 16 + ml;
    float bv = bias[n];
#pragma unroll
    for (int im = 0; im < 4; ++im)
#pragma unroll
      for (int r = 0; r < 4; ++r) {
        int m = m0 + wm + im * 16 + quad * 4 + r;
        out[(size_t)m * DIM + n] = acc[im][in_][r] + bv;
      }
  }
}

extern "C" void kernel_launch(void* const* d_in, const int* in_sizes, int n_in,
                              void* d_out, int out_size, void* d_ws, size_t ws_size,
                              hipStream_t stream) {
  const float* x      = (const float*)d_in[0];
  const float* W_qkv  = (const float*)d_in[1];
  const float* b_qkv  = (const float*)d_in[2];
  const float* W_proj = (const float*)d_in[3];
  const float* b_proj = (const float*)d_in[4];
  float* out = (float*)d_out;

  char* ws = (char*)d_ws;
  ushort* Xb  = (ushort*)(ws);
  ushort* Wqt = (ushort*)(ws + 16777216ull);
  ushort* Qw  = (ushort*)(ws + 23068672ull);
  ushort* Kw  = (ushort*)(ws + 39845888ull);
  ushort* Vtw = (ushort*)(ws + 56623104ull);
  ushort* Wph = (ushort*)(ws + 73400320ull);
  ushort* Wpl = (ushort*)(ws + 75497472ull);
  ushort* Ohw = Xb;   // Xb dead after qkv_mfma
  ushort* Olw = Qw;   // each attn block reads its Q tile before writing it

  cast_x<<<dim3(4096), 256, 0, stream>>>(x, Xb);
  tcast<false><<<dim3(48, 16), 256, 0, stream>>>(W_qkv, DIM, 3 * DIM, Wqt, nullptr);
  tcast<true><<<dim3(16, 16), 256, 0, stream>>>(W_proj, DIM, DIM, Wph, Wpl);
  qkv_mfma<<<dim3(24, 64), 256, 0, stream>>>(Xb, Wqt, b_qkv, Qw, Kw, Vtw);
  attn_kernel<<<dim3(2048), 256, 0, stream>>>(Qw, Kw, Vtw, Ohw, Olw);
  proj_mfma<<<dim3(8, 64), 256, 0, stream>>>(Ohw, Olw, Wph, Wpl, b_proj, out);
}

// Round 7
// 446.229 us; speedup vs baseline: 1.0637x; 1.0637x over previous
//
#include <hip/hip_runtime.h>

#define DIM   1024
#define SEQ   2048
#define NH    16
#define HD    64

typedef __attribute__((ext_vector_type(8))) short frag_ab;
typedef __attribute__((ext_vector_type(4))) float f32x4;

__device__ __forceinline__ ushort f32_bf16_rne(float f) {
  union { float f; unsigned int u; } v; v.f = f;
  unsigned int u = v.u + 0x7FFFu + ((v.u >> 16) & 1u);
  return (ushort)(u >> 16);
}

__device__ __forceinline__ void split_bf16(float f, ushort& h, ushort& l) {
  h = f32_bf16_rne(f);
  union { unsigned int u; float f; } hv; hv.u = ((unsigned int)h) << 16;
  l = f32_bf16_rne(f - hv.f);
}

__device__ __forceinline__ void gl2lds16(const void* g, void* l) {
  __builtin_amdgcn_global_load_lds(
      (const __attribute__((address_space(1))) unsigned int*)g,
      (__attribute__((address_space(3))) unsigned int*)l, 16, 0, 0);
}

__device__ __forceinline__ unsigned int asuint(float f) {
  union { float f; unsigned int u; } v; v.f = f; return v.u;
}

#if __has_builtin(__builtin_amdgcn_exp2f)
#define EXP2F(x) __builtin_amdgcn_exp2f(x)
#else
#define EXP2F(x) exp2f(x)
#endif

#if __has_builtin(__builtin_amdgcn_sched_barrier)
#define SCHED_FENCE() __builtin_amdgcn_sched_barrier(0)
#else
#define SCHED_FENCE() asm volatile("" ::: "memory")
#endif

// ---------------------------------------------------------------------------
// cast_x: fp32 -> bf16 copy.
// ---------------------------------------------------------------------------
__global__ __launch_bounds__(256) void cast_x(const float* __restrict__ x,
                                              ushort* __restrict__ xb) {
  int i = (blockIdx.x * 256 + threadIdx.x) * 8;
  float4 a = *(const float4*)(x + i);
  float4 b = *(const float4*)(x + i + 4);
  uint4 o;
  o.x = (unsigned int)f32_bf16_rne(a.x) | ((unsigned int)f32_bf16_rne(a.y) << 16);
  o.y = (unsigned int)f32_bf16_rne(a.z) | ((unsigned int)f32_bf16_rne(a.w) << 16);
  o.z = (unsigned int)f32_bf16_rne(b.x) | ((unsigned int)f32_bf16_rne(b.y) << 16);
  o.w = (unsigned int)f32_bf16_rne(b.z) | ((unsigned int)f32_bf16_rne(b.w) << 16);
  *(uint4*)(xb + i) = o;
}

// ---------------------------------------------------------------------------
// tcast: transpose + cast W [K][N] f32 -> Wt [N][K] bf16 (opt. hi/lo split).
// ---------------------------------------------------------------------------
template <bool SPLIT>
__global__ __launch_bounds__(256) void tcast(const float* __restrict__ in,
                                             int K, int N,
                                             ushort* __restrict__ outh,
                                             ushort* __restrict__ outl) {
  __shared__ __align__(16) ushort Th[64][72];
  __shared__ __align__(16) ushort Tl[64][72];
  const int kb = blockIdx.y * 64, nb = blockIdx.x * 64;
  const int t = threadIdx.x;
  const int kr = t >> 4, nc = (t & 15) * 4;
#pragma unroll
  for (int j = 0; j < 4; ++j) {
    int k = kr + j * 16;
    float4 v = *(const float4*)&in[(size_t)(kb + k) * N + nb + nc];
    float vv[4] = {v.x, v.y, v.z, v.w};
#pragma unroll
    for (int i = 0; i < 4; ++i) {
      if (SPLIT) {
        ushort h, l; split_bf16(vv[i], h, l);
        Th[nc + i][k] = h; Tl[nc + i][k] = l;
      } else {
        Th[nc + i][k] = f32_bf16_rne(vv[i]);
      }
    }
  }
  __syncthreads();
  const int n = t >> 2, kc = (t & 3) * 16;
  *(uint4*)&outh[(size_t)(nb + n) * K + kb + kc]     = *(const uint4*)&Th[n][kc];
  *(uint4*)&outh[(size_t)(nb + n) * K + kb + kc + 8] = *(const uint4*)&Th[n][kc + 8];
  if (SPLIT) {
    *(uint4*)&outl[(size_t)(nb + n) * K + kb + kc]     = *(const uint4*)&Tl[n][kc];
    *(uint4*)&outl[(size_t)(nb + n) * K + kb + kc + 8] = *(const uint4*)&Tl[n][kc + 8];
  }
}

// ---------------------------------------------------------------------------
// qkv_mfma (verified r2-r6): C = Xb @ Wqt^T (+bias) -> Q, K, V^T bf16.
// K is pre-scaled by SCALE*log2(e) so the attn score MFMA output is directly
// the exp2 argument.
// ---------------------------------------------------------------------------
__global__ __launch_bounds__(256) void qkv_mfma(
    const ushort* __restrict__ Xb, const ushort* __restrict__ Wqt,
    const float* __restrict__ bias,
    ushort* __restrict__ Qw, ushort* __restrict__ Kw, ushort* __restrict__ Vtw) {
  __shared__ __align__(16) ushort As[128 * 32];
  __shared__ __align__(16) ushort Bs[128 * 32];
  const int t = threadIdx.x, wave = t >> 6, lane = t & 63;
  const int ml = lane & 15, quad = lane >> 4;
  const int m0 = blockIdx.y * 128, n0 = blockIdx.x * 128;
  const int wm = (wave & 1) * 64, wn = (wave >> 1) * 64;
  const int srow = lane >> 2, scol = (lane & 3) * 8;
  const int r0 = wave * 16, r1 = (4 + wave) * 16;

  const ushort* Ag = Xb  + (size_t)(m0 + srow) * DIM + scol;
  const ushort* Bg = Wqt + (size_t)(n0 + srow) * DIM + scol;

  f32x4 acc[4][4];
#pragma unroll
  for (int i = 0; i < 4; ++i)
#pragma unroll
    for (int j = 0; j < 4; ++j) acc[i][j] = (f32x4){0.f, 0.f, 0.f, 0.f};

  for (int k0 = 0; k0 < DIM; k0 += 32) {
    __syncthreads();
    gl2lds16(Ag + (size_t)r0 * DIM + k0, &As[r0 * 32]);
    gl2lds16(Ag + (size_t)r1 * DIM + k0, &As[r1 * 32]);
    gl2lds16(Bg + (size_t)r0 * DIM + k0, &Bs[r0 * 32]);
    gl2lds16(Bg + (size_t)r1 * DIM + k0, &Bs[r1 * 32]);
    __syncthreads();
    frag_ab af[4], bfr[4];
#pragma unroll
    for (int im = 0; im < 4; ++im)
      af[im] = *(const frag_ab*)&As[(wm + im * 16 + ml) * 32 + quad * 8];
#pragma unroll
    for (int in_ = 0; in_ < 4; ++in_)
      bfr[in_] = *(const frag_ab*)&Bs[(wn + in_ * 16 + ml) * 32 + quad * 8];
#pragma unroll
    for (int im = 0; im < 4; ++im)
#pragma unroll
      for (int in_ = 0; in_ < 4; ++in_)
        acc[im][in_] = __builtin_amdgcn_mfma_f32_16x16x32_bf16(
            af[im], bfr[in_], acc[im][in_], 0, 0, 0);
  }

  const int t3 = n0 >> 10;
  const int b  = m0 >> 11;
  const int s0 = (m0 & (SEQ - 1)) + wm + quad * 4;
#pragma unroll
  for (int in_ = 0; in_ < 4; ++in_) {
    int n = n0 + wn + in_ * 16 + ml;
    int h = (n >> 6) & 15, d = n & 63;
    float bv = bias[n];
    size_t bh = (size_t)(b * NH + h);
    if (t3 == 2) {
#pragma unroll
      for (int im = 0; im < 4; ++im) {
        int s = s0 + im * 16;
        ushort4 v;
        v.x = f32_bf16_rne(acc[im][in_][0] + bv);
        v.y = f32_bf16_rne(acc[im][in_][1] + bv);
        v.z = f32_bf16_rne(acc[im][in_][2] + bv);
        v.w = f32_bf16_rne(acc[im][in_][3] + bv);
        *(ushort4*)&Vtw[(bh * HD + d) * SEQ + s] = v;
      }
    } else {
      ushort* dst = (t3 == 0) ? Qw : Kw;
      const float m = (t3 == 0) ? 1.0f : 0.18033688011112043f; // SCALE*log2e
#pragma unroll
      for (int im = 0; im < 4; ++im)
#pragma unroll
        for (int r = 0; r < 4; ++r)
          dst[(bh * SEQ + s0 + im * 16 + r) * HD + d] =
              f32_bf16_rne((acc[im][in_][r] + bv) * m);
    }
  }
}

// ---------------------------------------------------------------------------
// attn: barrier-free flash attention (round-6 verified structure) + ONE
// change: a scheduler fence between the per-chunk load group and the compute
// group. Without it the compiler interleaves load->use->load->use and each
// use pays the full ~400-cycle L2 latency (12x/chunk = the observed ~4.7k
// cycle/chunk stall). With the fence, all 12 loads issue back-to-back and
// pipeline: first use waits vmcnt(11) -> one latency exposure per chunk.
// ---------------------------------------------------------------------------
__global__ __launch_bounds__(256, 3) void attn_kernel(
    const ushort* Qw, const ushort* __restrict__ Kw,
    const ushort* __restrict__ Vtw, ushort* Ohw, ushort* Olw) {
  __shared__ __align__(16) char smem[17664];
  float* Ored = (float*)smem;                  // [64][65] f32 (16640 B)
  float* lsum_buf = (float*)(smem + 16640);    // [4][64]  f32 (1024 B)

  const int t = threadIdx.x, wave = t >> 6, lane = t & 63;
  const int ml = lane & 15, quad = lane >> 4;
  const int bid = blockIdx.x;
  const int bh  = (bid & 7) | ((bid >> 8) << 3);
  const int qt0 = (bid >> 3) & 31;

  const ushort* Qg = Qw + ((size_t)bh * SEQ + qt0 * 64) * HD;
  const ushort* Kg = Kw + ((size_t)bh * SEQ + wave * 512) * HD;
  const ushort* Vg = Vtw + (size_t)bh * HD * SEQ + wave * 512;

  // Q fragments: held in registers for the whole kernel
  frag_ab qf[4][2];
#pragma unroll
  for (int qt = 0; qt < 4; ++qt)
#pragma unroll
    for (int h = 0; h < 2; ++h)
      qf[qt][h] = *(const frag_ab*)&Qg[(qt * 16 + ml) * HD + h * 32 + quad * 8];

  f32x4 acc[4][4];
#pragma unroll
  for (int i = 0; i < 4; ++i)
#pragma unroll
    for (int j = 0; j < 4; ++j) acc[i][j] = (f32x4){0.f, 0.f, 0.f, 0.f};
  float lsum[4] = {0.f, 0.f, 0.f, 0.f};

#pragma unroll 1
  for (int c = 0; c < 16; ++c) {
    const int k0 = c * 32;
    // ---- load group: all 12 loads issue before any compute ----
    frag_ab ak00 = *(const frag_ab*)&Kg[(k0 + ml) * HD + quad * 8];
    frag_ab ak01 = *(const frag_ab*)&Kg[(k0 + ml) * HD + 32 + quad * 8];
    frag_ab ak10 = *(const frag_ab*)&Kg[(k0 + 16 + ml) * HD + quad * 8];
    frag_ab ak11 = *(const frag_ab*)&Kg[(k0 + 16 + ml) * HD + 32 + quad * 8];
    // V fragments in the PERMUTED key order matching P below:
    // j=0..3 -> keys k0+4*quad+j ; j=4..7 -> keys k0+16+4*quad+(j-4)
    frag_ab av[4];
#pragma unroll
    for (int dt = 0; dt < 4; ++dt) {
      const ushort* vrow = Vg + (size_t)(dt * 16 + ml) * SEQ + k0 + 4 * quad;
      union { uint2 h[2]; frag_ab f; } u;
      u.h[0] = *(const uint2*)(vrow);
      u.h[1] = *(const uint2*)(vrow + 16);
      av[dt] = u.f;
    }
    SCHED_FENCE();   // loads above, compute below — no interleave

#pragma unroll
    for (int qt = 0; qt < 4; ++qt) {
      f32x4 s0 = __builtin_amdgcn_mfma_f32_16x16x32_bf16(
          ak00, qf[qt][0], (f32x4){0.f, 0.f, 0.f, 0.f}, 0, 0, 0);
      s0 = __builtin_amdgcn_mfma_f32_16x16x32_bf16(ak01, qf[qt][1], s0, 0, 0, 0);
      f32x4 s1 = __builtin_amdgcn_mfma_f32_16x16x32_bf16(
          ak10, qf[qt][0], (f32x4){0.f, 0.f, 0.f, 0.f}, 0, 0, 0);
      s1 = __builtin_amdgcn_mfma_f32_16x16x32_bf16(ak11, qf[qt][1], s1, 0, 0, 0);
      float e0 = EXP2F(s0[0]), e1 = EXP2F(s0[1]);
      float e2 = EXP2F(s0[2]), e3 = EXP2F(s0[3]);
      float e4 = EXP2F(s1[0]), e5 = EXP2F(s1[1]);
      float e6 = EXP2F(s1[2]), e7 = EXP2F(s1[3]);
      lsum[qt] += ((e0 + e1) + (e2 + e3)) + ((e4 + e5) + (e6 + e7));
      union { unsigned int i[4]; frag_ab f; } pv;
      pv.i[0] = __builtin_amdgcn_perm(asuint(e1) + 0x8000u,
                                      asuint(e0) + 0x8000u, 0x07060302u);
      pv.i[1] = __builtin_amdgcn_perm(asuint(e3) + 0x8000u,
                                      asuint(e2) + 0x8000u, 0x07060302u);
      pv.i[2] = __builtin_amdgcn_perm(asuint(e5) + 0x8000u,
                                      asuint(e4) + 0x8000u, 0x07060302u);
      pv.i[3] = __builtin_amdgcn_perm(asuint(e7) + 0x8000u,
                                      asuint(e6) + 0x8000u, 0x07060302u);
#pragma unroll
      for (int dt = 0; dt < 4; ++dt)
        acc[dt][qt] = __builtin_amdgcn_mfma_f32_16x16x32_bf16(
            av[dt], pv.f, acc[dt][qt], 0, 0, 0);
    }
  }

  // quad-reduce lsum within wave (each lane covered 8 keys/chunk; quads tile 32)
#pragma unroll
  for (int qt = 0; qt < 4; ++qt) {
    float s = lsum[qt];
    s += __shfl_xor(s, 16, 64);
    s += __shfl_xor(s, 32, 64);
    lsum[qt] = s;
  }

  __syncthreads();   // only block barrier: all waves done with their K-loop
  if (quad == 0) {
#pragma unroll
    for (int qt = 0; qt < 4; ++qt) lsum_buf[wave * 64 + qt * 16 + ml] = lsum[qt];
  }
  if (wave == 0) {
#pragma unroll
    for (int dt = 0; dt < 4; ++dt)
#pragma unroll
      for (int qt = 0; qt < 4; ++qt)
#pragma unroll
        for (int r = 0; r < 4; ++r)
          Ored[(dt * 16 + quad * 4 + r) * 65 + qt * 16 + ml] = acc[dt][qt][r];
  }
  __syncthreads();
  if (wave != 0) {
#pragma unroll
    for (int dt = 0; dt < 4; ++dt)
#pragma unroll
      for (int qt = 0; qt < 4; ++qt)
#pragma unroll
        for (int r = 0; r < 4; ++r)
          atomicAdd(&Ored[(dt * 16 + quad * 4 + r) * 65 + qt * 16 + ml],
                    acc[dt][qt][r]);
  }
  __syncthreads();

  // normalize + hi/lo bf16 split, coalesced store
  const int q = t >> 2, d0 = (t & 3) * 16;
  const float inv = 1.0f / (lsum_buf[q] + lsum_buf[64 + q] +
                            lsum_buf[128 + q] + lsum_buf[192 + q]);
  size_t rowb = ((size_t)bh * SEQ + qt0 * 64 + q) * HD + d0;
#pragma unroll
  for (int g = 0; g < 2; ++g) {
    unsigned int hu[4], lu[4];
#pragma unroll
    for (int j = 0; j < 4; ++j) {
      float f0 = Ored[(d0 + g * 8 + 2 * j) * 65 + q] * inv;
      float f1 = Ored[(d0 + g * 8 + 2 * j + 1) * 65 + q] * inv;
      ushort h0, l0, h1, l1;
      split_bf16(f0, h0, l0);
      split_bf16(f1, h1, l1);
      hu[j] = (unsigned int)h0 | ((unsigned int)h1 << 16);
      lu[j] = (unsigned int)l0 | ((unsigned int)l1 << 16);
    }
    uint4 hv = {hu[0], hu[1], hu[2], hu[3]};
    uint4 lv = {lu[0], lu[1], lu[2], lu[3]};
    *(uint4*)&Ohw[rowb + g * 8] = hv;
    *(uint4*)&Olw[rowb + g * 8] = lv;
  }
}

// ---------------------------------------------------------------------------
// proj_mfma (verified): out = (Oh+Ol) @ (Wh+Wl)^T + bias.
// ---------------------------------------------------------------------------
__global__ __launch_bounds__(256) void proj_mfma(
    const ushort* __restrict__ Oh, const ushort* __restrict__ Ol,
    const ushort* __restrict__ Wph, const ushort* __restrict__ Wpl,
    const float* __restrict__ bias, float* __restrict__ out) {
  __shared__ __align__(16) ushort As[128 * 32];
  __shared__ __align__(16) ushort Bs[128 * 32];
  const int t = threadIdx.x, wave = t >> 6, lane = t & 63;
  const int ml = lane & 15, quad = lane >> 4;
  const int m0 = blockIdx.y * 128, n0 = blockIdx.x * 128;
  const int wm = (wave & 1) * 64, wn = (wave >> 1) * 64;
  const int srow = lane >> 2, scol = (lane & 3) * 8;
  const int r0 = wave * 16, r1 = (4 + wave) * 16;
  const int b = m0 >> 11, s0r = m0 & (SEQ - 1);

  f32x4 acc[4][4];
#pragma unroll
  for (int i = 0; i < 4; ++i)
#pragma unroll
    for (int j = 0; j < 4; ++j) acc[i][j] = (f32x4){0.f, 0.f, 0.f, 0.f};

  for (int kt = 0; kt < 96; ++kt) {
    int ph = kt >> 5;
    int kv = (kt & 31) * 32;
    const ushort* Asrc = (ph == 1) ? Ol : Oh;
    const ushort* Bsrc = (ph == 2) ? Wpl : Wph;
    int h = kv >> 6, dbase = kv & 63;
    const ushort* Ag = Asrc + (((size_t)(b * NH + h) * SEQ) + s0r + srow) * HD
                            + dbase + scol;
    const ushort* Bg = Bsrc + (size_t)(n0 + srow) * DIM + kv + scol;
    __syncthreads();
    gl2lds16(Ag + (size_t)r0 * HD, &As[r0 * 32]);
    gl2lds16(Ag + (size_t)r1 * HD, &As[r1 * 32]);
    gl2lds16(Bg + (size_t)r0 * DIM, &Bs[r0 * 32]);
    gl2lds16(Bg + (size_t)r1 * DIM, &Bs[r1 * 32]);
    __syncthreads();
    frag_ab af[4], bfr[4];
#pragma unroll
    for (int im = 0; im < 4; ++im)
      af[im] = *(const frag_ab*)&As[(wm + im * 16 + ml) * 32 + quad * 8];
#pragma unroll
    for (int in_ = 0; in_ < 4; ++in_)
      bfr[in_] = *(const frag_ab*)&Bs[(wn + in_ * 16 + ml) * 32 + quad * 8];
#pragma unroll
    for (int im = 0; im < 4; ++im)
#pragma unroll
      for (int in_ = 0; in_ < 4; ++in_)
        acc[im][in_] = __builtin_amdgcn_mfma_f32_16x16x32_bf16(
            af[im], bfr[in_], acc[im][in_], 0, 0, 0);
  }

#pragma unroll
  for (int in_ = 0; in_ < 4; ++in_) {
    int n = n0 + wn + in_ * 16 + ml;
    float bv = bias[n];
#pragma unroll
    for (int im = 0; im < 4; ++im)
#pragma unroll
      for (int r = 0; r < 4; ++r) {
        int m = m0 + wm + im * 16 + quad * 4 + r;
        out[(size_t)m * DIM + n] = acc[im][in_][r] + bv;
      }
  }
}

extern "C" void kernel_launch(void* const* d_in, const int* in_sizes, int n_in,
                              void* d_out, int out_size, void* d_ws, size_t ws_size,
                              hipStream_t stream) {
  const float* x      = (const float*)d_in[0];
  const float* W_qkv  = (const float*)d_in[1];
  const float* b_qkv  = (const float*)d_in[2];
  const float* W_proj = (const float*)d_in[3];
  const float* b_proj = (const float*)d_in[4];
  float* out = (float*)d_out;

  char* ws = (char*)d_ws;
  ushort* Xb  = (ushort*)(ws);
  ushort* Wqt = (ushort*)(ws + 16777216ull);
  ushort* Qw  = (ushort*)(ws + 23068672ull);
  ushort* Kw  = (ushort*)(ws + 39845888ull);
  ushort* Vtw = (ushort*)(ws + 56623104ull);
  ushort* Wph = (ushort*)(ws + 73400320ull);
  ushort* Wpl = (ushort*)(ws + 75497472ull);
  ushort* Ohw = Xb;   // Xb dead after qkv_mfma
  ushort* Olw = Qw;   // each attn block reads its Q tile before writing it

  cast_x<<<dim3(4096), 256, 0, stream>>>(x, Xb);
  tcast<false><<<dim3(48, 16), 256, 0, stream>>>(W_qkv, DIM, 3 * DIM, Wqt, nullptr);
  tcast<true><<<dim3(16, 16), 256, 0, stream>>>(W_proj, DIM, DIM, Wph, Wpl);
  qkv_mfma<<<dim3(24, 64), 256, 0, stream>>>(Xb, Wqt, b_qkv, Qw, Kw, Vtw);
  attn_kernel<<<dim3(2048), 256, 0, stream>>>(Qw, Kw, Vtw, Ohw, Olw);
  proj_mfma<<<dim3(8, 64), 256, 0, stream>>>(Ohw, Olw, Wph, Wpl, b_proj, out);
}